// Round 4
// baseline (2703.266 us; speedup 1.0000x reference)
//
#include <hip/hip_runtime.h>
#include <hip/hip_bf16.h>

// Problem constants (reference: B=2,S=2048 -> T=4096; H=1024, I=4096, E=8, 2 steps)
#define T_TOK 4096
#define H_DIM 1024
#define I_DIM 4096
#define E_EXP 8
#define RMS_EPS_F 1e-6f

using bf16x8 = __attribute__((ext_vector_type(8))) __bf16;
using f32x4  = __attribute__((ext_vector_type(4))) float;

__device__ inline void gload_lds16(const void* g, void* l) {
    __builtin_amdgcn_global_load_lds(
        (const __attribute__((address_space(1))) void*)g,
        (__attribute__((address_space(3))) void*)l,
        16, 0, 0);
}

// -------- transpose + fp32->bf16 convert: in [R][C] -> out [C][R], batched over blockIdx.z
__global__ __launch_bounds__(256) void k_transpose_cvt(
    const float* __restrict__ in, __hip_bfloat16* __restrict__ out, int R, int C)
{
    __shared__ float tile[32][33];
    const size_t mat = (size_t)R * C;
    in  += (size_t)blockIdx.z * mat;
    out += (size_t)blockIdx.z * mat;
    const int c0 = blockIdx.x * 32, r0 = blockIdx.y * 32;
    const int tx = threadIdx.x & 31, ty = threadIdx.x >> 5;   // 32 x 8
#pragma unroll
    for (int dy = 0; dy < 32; dy += 8)
        tile[ty + dy][tx] = in[(size_t)(r0 + ty + dy) * C + (c0 + tx)];
    __syncthreads();
#pragma unroll
    for (int dy = 0; dy < 32; dy += 8)
        out[(size_t)(c0 + ty + dy) * R + (r0 + tx)] = __float2bfloat16(tile[tx][ty + dy]);
}

// -------- token prep: x [T,H] fp32 -> tb [T,H] bf16, optional rmsnorm*ln_w. 1 block/token.
__global__ __launch_bounds__(256) void k_prep(
    const float* __restrict__ x, const float* __restrict__ lnw,
    __hip_bfloat16* __restrict__ tb, int do_norm)
{
    const int t = blockIdx.x;
    const float* row = x + (size_t)t * H_DIM;
    const int base = threadIdx.x * 4;
    float4 v = *(const float4*)(row + base);
    if (do_norm) {
        float ss = v.x*v.x + v.y*v.y + v.z*v.z + v.w*v.w;
#pragma unroll
        for (int off = 32; off > 0; off >>= 1) ss += __shfl_xor(ss, off);
        __shared__ float wsum[4];
        const int w = threadIdx.x >> 6;
        if ((threadIdx.x & 63) == 0) wsum[w] = ss;
        __syncthreads();
        const float tot = wsum[0] + wsum[1] + wsum[2] + wsum[3];
        const float scale = rsqrtf(tot * (1.0f / H_DIM) + RMS_EPS_F);
        float4 g = *(const float4*)(lnw + base);
        v.x *= scale * g.x; v.y *= scale * g.y; v.z *= scale * g.z; v.w *= scale * g.w;
    }
    __hip_bfloat16* o = tb + (size_t)t * H_DIM + base;
    o[0] = __float2bfloat16(v.x); o[1] = __float2bfloat16(v.y);
    o[2] = __float2bfloat16(v.z); o[3] = __float2bfloat16(v.w);
}

// -------- gate: logits = tb @ gate_w^T, softmax over E=8. One wave per token.
__global__ __launch_bounds__(256) void k_gate(
    const __hip_bfloat16* __restrict__ tb, const float* __restrict__ gw,
    float* __restrict__ rw)
{
    const int t = blockIdx.x * 4 + (threadIdx.x >> 6);
    const int lane = threadIdx.x & 63;
    const __hip_bfloat16* row = tb + (size_t)t * H_DIM;
    float acc[E_EXP];
#pragma unroll
    for (int e = 0; e < E_EXP; ++e) acc[e] = 0.f;
    for (int h = lane; h < H_DIM; h += 64) {
        const float xv = __bfloat162float(row[h]);
#pragma unroll
        for (int e = 0; e < E_EXP; ++e) acc[e] += xv * gw[e * H_DIM + h];
    }
#pragma unroll
    for (int e = 0; e < E_EXP; ++e) {
#pragma unroll
        for (int off = 32; off > 0; off >>= 1) acc[e] += __shfl_xor(acc[e], off);
    }
    if (lane == 0) {
        float mx = acc[0];
#pragma unroll
        for (int e = 1; e < E_EXP; ++e) mx = fmaxf(mx, acc[e]);
        float ex[E_EXP], s = 0.f;
#pragma unroll
        for (int e = 0; e < E_EXP; ++e) { ex[e] = __expf(acc[e] - mx); s += ex[e]; }
        const float inv = 1.f / s;
#pragma unroll
        for (int e = 0; e < E_EXP; ++e) rw[(size_t)t * E_EXP + e] = ex[e] * inv;
    }
}

// ======== 256x256 8-phase GEMM (T1+T2+T3+T4+T5), C = A[M,K] @ Bt[N,K]^T, batched over z.
// 8 waves (2 M x 4 N), per-wave 128x64 = acc[8][4] of 16x16 frags, BK=64.
// Round-4 deltas vs round-3: (a) register read-ahead — q1..q3 fragments issued
// under q0's MFMA (sched_barrier-pinned), (b) grid x=M-tile fastest + bijective
// XCD chunk swizzle. Stage/barrier/vmcnt ledger is IDENTICAL to round-3 (verified).

template<int MB, int NB>
__device__ __forceinline__ void mfma_q(const bf16x8 (&a)[4][2], const bf16x8 (&b)[2][2],
                                       f32x4 (&acc)[8][4]) {
    __builtin_amdgcn_s_setprio(1);
#pragma unroll
    for (int mi = 0; mi < 4; ++mi)
#pragma unroll
        for (int nn = 0; nn < 2; ++nn)
#pragma unroll
            for (int kc = 0; kc < 2; ++kc)
                acc[MB + mi][NB + nn] = __builtin_amdgcn_mfma_f32_16x16x32_bf16(
                    a[mi][kc], b[nn][kc], acc[MB + mi][NB + nn], 0, 0, 0);
    __builtin_amdgcn_s_setprio(0);
}

template<int BB, int MBASE>
__device__ __forceinline__ void ld_a(bf16x8 (&a)[4][2], const char* rdA, int kof0, int kof1) {
#pragma unroll
    for (int mi = 0; mi < 4; ++mi) {
        a[mi][0] = *(const bf16x8*)(rdA + BB * 32768 + (MBASE + mi) * 2048 + kof0);
        a[mi][1] = *(const bf16x8*)(rdA + BB * 32768 + (MBASE + mi) * 2048 + kof1);
    }
}
template<int BB, int NBASE>
__device__ __forceinline__ void ld_b(bf16x8 (&b)[2][2], const char* rdB, int kof0, int kof1) {
#pragma unroll
    for (int ni = 0; ni < 2; ++ni) {
        b[ni][0] = *(const bf16x8*)(rdB + BB * 32768 + (NBASE + ni) * 2048 + kof0);
        b[ni][1] = *(const bf16x8*)(rdB + BB * 32768 + (NBASE + ni) * 2048 + kof1);
    }
}

#define BAR()   __builtin_amdgcn_s_barrier()
#define LGKM0() asm volatile("s_waitcnt lgkmcnt(0)")
#define VMW(n)  asm volatile("s_waitcnt vmcnt(" #n ")" ::: "memory")
#define SCHED0() __builtin_amdgcn_sched_barrier(0)

template <int MODE>
__global__ __launch_bounds__(512, 2) void k_gemm8(
    const __hip_bfloat16* __restrict__ A, int lda, long long strideA,
    const __hip_bfloat16* __restrict__ Bt, int ldb, long long strideB,
    const float* __restrict__ bias, int strideBias,
    void* __restrict__ out, int ldo, long long strideOut, int K)
{
    __shared__ __hip_bfloat16 sA[2][2][128 * 64];   // 64 KB
    __shared__ __hip_bfloat16 sB[2][2][128 * 64];   // 64 KB

    // ---- T1: bijective XCD chunk swizzle on the flat id (x fastest in HW dispatch).
    // grid.x = M-tiles (blocks sharing a weight panel adjacent), nwg % 8 == 0 for all shapes here.
    const int gx = gridDim.x, gy = gridDim.y;
    const int nwg = gx * gy * gridDim.z;
    int id = blockIdx.x + gx * (blockIdx.y + gy * blockIdx.z);
    id = (id & 7) * (nwg >> 3) + (id >> 3);
    const int z   = id / (gx * gy);
    const int rem = id - z * (gx * gy);
    const int byy = rem / gx;
    const int bxx = rem - byy * gx;
    const int m0 = bxx * 256, n0 = byy * 256;

    A  += (size_t)z * (size_t)strideA;
    Bt += (size_t)z * (size_t)strideB;

    const int tid  = threadIdx.x;
    const int lane = tid & 63;
    const int wid  = tid >> 6;
    const int wr = wid >> 2, wc = wid & 3;          // 2 x 4 waves

    // ---- staging: dest linear (tid*16); source col pre-swizzled by involution kbyte ^= (row&7)<<4
    const int sr  = tid >> 3;
    const int skb = ((((tid & 7) * 16) ^ ((sr & 7) << 4)) >> 1);
    const __hip_bfloat16* gA = A  + (size_t)(m0 + sr) * lda + skb;
    const __hip_bfloat16* gB = Bt + (size_t)(n0 + sr) * ldb + skb;
    char* const dA = (char*)&sA[0][0][0] + tid * 16;
    char* const dB = (char*)&sB[0][0][0] + tid * 16;

#define STAGE_A(bb, hh, kt) do { \
    const __hip_bfloat16* s_ = gA + (size_t)(hh) * 128 * lda + (size_t)(kt) * 64; \
    gload_lds16(s_,                     dA + (bb) * 32768 + (hh) * 16384); \
    gload_lds16(s_ + (size_t)64 * lda,  dA + (bb) * 32768 + (hh) * 16384 + 8192); \
} while (0)
#define STAGE_B(bb, hh, kt) do { \
    const __hip_bfloat16* s_ = gB + (size_t)(hh) * 128 * ldb + (size_t)(kt) * 64; \
    gload_lds16(s_,                     dB + (bb) * 32768 + (hh) * 16384); \
    gload_lds16(s_ + (size_t)64 * ldb,  dB + (bb) * 32768 + (hh) * 16384 + 8192); \
} while (0)

    // ---- ds_read fragment addressing (swizzled)
    const int fr = lane & 15, kg = lane >> 4;
    const int msk  = (fr & 7) << 4;
    const int kof0 = (kg * 16) ^ msk;
    const int kof1 = (64 + kg * 16) ^ msk;
    const char* rdA = (const char*)&sA[0][wr][0] + fr * 128;
    const char* rdB = (const char*)&sB[0][wc >> 1][0] + (wc & 1) * 8192 + fr * 128;

    f32x4  acc[8][4] = {};
    bf16x8 aL[4][2], aH[4][2], bL[2][2], bH[2][2];

    const int NT = K >> 6;                          // K-tiles of 64 (even, >= 4)

    // ---- prologue: stage T0 (B,A) and T1 (B). Ledger: 12 issued, VMW(4) lands T0, leaves B(1).
    STAGE_B(0, 0, 0); STAGE_B(0, 1, 0);
    STAGE_A(0, 0, 0); STAGE_A(0, 1, 0);
    STAGE_B(1, 0, 1); STAGE_B(1, 1, 1);
    VMW(4); BAR(); SCHED0();

    for (int i = 0; i < NT / 2 - 1; ++i) {
        const int t1 = 2 * i + 1;
        // ===== K-tile t0 (buf0); stages: A(t1)->buf1, B(t1+1)->buf0
        ld_a<0, 0>(aL, rdA, kof0, kof1);            // q0 operands (12 reads)
        ld_b<0, 0>(bL, rdB, kof0, kof1);
        STAGE_A(1, 0, t1);
        BAR(); LGKM0();
        ld_b<0, 2>(bH, rdB, kof0, kof1);            // read-ahead under q0 MFMA (12 reads)
        ld_a<0, 4>(aH, rdA, kof0, kof1);
        SCHED0();
        mfma_q<0, 0>(aL, bL, acc);
        BAR();
        STAGE_A(1, 1, t1);
        BAR();
        mfma_q<0, 2>(aL, bH, acc);
        BAR();
        STAGE_B(0, 0, t1 + 1);
        BAR();
        mfma_q<4, 0>(aH, bL, acc);
        BAR();
        STAGE_B(0, 1, t1 + 1);
        BAR();
        mfma_q<4, 2>(aH, bH, acc);
        VMW(4); BAR(); SCHED0();
        // ===== K-tile t1 (buf1); stages: A(t1+1)->buf0, B(t1+2)->buf1
        ld_a<1, 0>(aL, rdA, kof0, kof1);
        ld_b<1, 0>(bL, rdB, kof0, kof1);
        STAGE_A(0, 0, t1 + 1);
        BAR(); LGKM0();
        ld_b<1, 2>(bH, rdB, kof0, kof1);
        ld_a<1, 4>(aH, rdA, kof0, kof1);
        SCHED0();
        mfma_q<0, 0>(aL, bL, acc);
        BAR();
        STAGE_A(0, 1, t1 + 1);
        BAR();
        mfma_q<0, 2>(aL, bH, acc);
        BAR();
        STAGE_B(1, 0, t1 + 2);
        BAR();
        mfma_q<4, 0>(aH, bL, acc);
        BAR();
        STAGE_B(1, 1, t1 + 2);
        BAR();
        mfma_q<4, 2>(aH, bH, acc);
        VMW(4); BAR(); SCHED0();
    }
    {   // ---- last iteration: tiles NT-2 (buf0), NT-1 (buf1); stage only A(NT-1); drain once.
        const int t1 = NT - 1;
        ld_a<0, 0>(aL, rdA, kof0, kof1);
        ld_b<0, 0>(bL, rdB, kof0, kof1);
        STAGE_A(1, 0, t1);
        BAR(); LGKM0();
        ld_b<0, 2>(bH, rdB, kof0, kof1);
        ld_a<0, 4>(aH, rdA, kof0, kof1);
        SCHED0();
        mfma_q<0, 0>(aL, bL, acc);
        BAR();
        STAGE_A(1, 1, t1);
        BAR();
        mfma_q<0, 2>(aL, bH, acc);
        BAR();
        BAR();
        mfma_q<4, 0>(aH, bL, acc);
        BAR();
        mfma_q<4, 2>(aH, bH, acc);
        VMW(0); BAR(); SCHED0();
        ld_a<1, 0>(aL, rdA, kof0, kof1);
        ld_b<1, 0>(bL, rdB, kof0, kof1);
        BAR(); LGKM0();
        ld_b<1, 2>(bH, rdB, kof0, kof1);
        ld_a<1, 4>(aH, rdA, kof0, kof1);
        SCHED0();
        mfma_q<0, 0>(aL, bL, acc);
        mfma_q<0, 2>(aL, bH, acc);
        mfma_q<4, 0>(aH, bL, acc);
        mfma_q<4, 2>(aH, bH, acc);
    }

    // ---- epilogue. C-frag layout: col = lane&15 (fr), row = kg*4 + j  [m89-verified]
    const int rB = kg * 4;
    if (MODE == 0) {
        __hip_bfloat16* O = (__hip_bfloat16*)out + (size_t)z * (size_t)strideOut;
        const float* bz = bias + (size_t)z * (size_t)strideBias;
#pragma unroll
        for (int mi = 0; mi < 8; ++mi) {
            const int gm = m0 + wr * 128 + mi * 16 + rB;
#pragma unroll
            for (int ni = 0; ni < 4; ++ni) {
                const int gn = n0 + wc * 64 + ni * 16 + fr;
                const float bv = bz[gn];
#pragma unroll
                for (int j = 0; j < 4; ++j) {
                    float v = acc[mi][ni][j] + bv;
                    v = v / (1.f + __expf(-v));        // silu
                    O[(size_t)(gm + j) * ldo + gn] = __float2bfloat16(v);
                }
            }
        }
    } else {
        float* O = (float*)out + (size_t)z * (size_t)strideOut;
#pragma unroll
        for (int mi = 0; mi < 8; ++mi) {
            const int gm = m0 + wr * 128 + mi * 16 + rB;
#pragma unroll
            for (int ni = 0; ni < 4; ++ni) {
                const int gn = n0 + wc * 64 + ni * 16 + fr;
#pragma unroll
                for (int j = 0; j < 4; ++j)
                    O[(size_t)(gm + j) * ldo + gn] = acc[mi][ni][j];
            }
        }
    }
#undef STAGE_A
#undef STAGE_B
}

// -------- combine: x[t,h] += sum_j rw[t,e0+j]*(eo[j][t][h] + b2[e0+j][h]). 1 block/token.
__global__ __launch_bounds__(256) void k_combine(
    const float* __restrict__ eo, const float* __restrict__ rw,
    const float* __restrict__ b2, float* __restrict__ x, int e0, int g)
{
    const int t = blockIdx.x;
    const int h = threadIdx.x * 4;
    float4 acc = *(const float4*)(x + (size_t)t * H_DIM + h);
    for (int j = 0; j < g; ++j) {
        const float w = rw[(size_t)t * E_EXP + e0 + j];
        const float4 v  = *(const float4*)(eo + ((size_t)j * T_TOK + t) * H_DIM + h);
        const float4 bz = *(const float4*)(b2 + (size_t)(e0 + j) * H_DIM + h);
        acc.x += w * (v.x + bz.x);
        acc.y += w * (v.y + bz.y);
        acc.z += w * (v.z + bz.z);
        acc.w += w * (v.w + bz.w);
    }
    *(float4*)(x + (size_t)t * H_DIM + h) = acc;
}

extern "C" void kernel_launch(void* const* d_in, const int* in_sizes, int n_in,
                              void* d_out, int out_size, void* d_ws, size_t ws_size,
                              hipStream_t stream)
{
    const float* hidden = (const float*)d_in[0];
    const float* gate_w = (const float*)d_in[1];
    const float* w1     = (const float*)d_in[2];
    const float* b1     = (const float*)d_in[3];
    const float* w2     = (const float*)d_in[4];
    const float* b2     = (const float*)d_in[5];
    const float* ln_w   = (const float*)d_in[6];
    float* x = (float*)d_out;

    // workspace carve
    const size_t w1t_b = (size_t)E_EXP * I_DIM * H_DIM * 2;   // 64 MB
    const size_t w2t_b = (size_t)E_EXP * H_DIM * I_DIM * 2;   // 64 MB
    const size_t tb_b  = (size_t)T_TOK * H_DIM * 2;           //  8 MB
    const size_t rw_b  = (size_t)T_TOK * E_EXP * 4;           // 128 KB
    const size_t hb1_b = (size_t)T_TOK * I_DIM * 2;           // 32 MB per expert
    const size_t eo1_b = (size_t)T_TOK * H_DIM * 4;           // 16 MB per expert
    const size_t base_b = w1t_b + w2t_b + tb_b + rw_b;

    // largest expert group that fits
    int g = 0;
    for (int cand = 8; cand >= 1; cand >>= 1)
        if (base_b + (size_t)cand * (hb1_b + eo1_b) <= ws_size) { g = cand; break; }

    char* ws = (char*)d_ws;
    __hip_bfloat16* w1t = (__hip_bfloat16*)ws;  ws += w1t_b;
    __hip_bfloat16* w2t = (__hip_bfloat16*)ws;  ws += w2t_b;
    __hip_bfloat16* tb  = (__hip_bfloat16*)ws;  ws += tb_b;
    float*          rw  = (float*)ws;           ws += rw_b;
    __hip_bfloat16* hb  = (__hip_bfloat16*)ws;
    float*          eo  = (float*)(ws + (size_t)(g > 0 ? g : 1) * hb1_b);

    // x = hidden_states (running residual lives in d_out)
    hipMemcpyAsync(x, hidden, (size_t)T_TOK * H_DIM * 4, hipMemcpyDeviceToDevice, stream);

    if (g == 0) return;  // ws too small (harness has given >= 232 MB so far)

    // bf16 weights in B^T layout: w1t [E][I][H], w2t [E][H][I]
    k_transpose_cvt<<<dim3(I_DIM / 32, H_DIM / 32, E_EXP), 256, 0, stream>>>(w1, w1t, H_DIM, I_DIM);
    k_transpose_cvt<<<dim3(H_DIM / 32, I_DIM / 32, E_EXP), 256, 0, stream>>>(w2, w2t, I_DIM, H_DIM);

    for (int step = 0; step < 2; ++step) {
        k_prep<<<T_TOK, 256, 0, stream>>>(x, ln_w, tb, step);
        k_gate<<<T_TOK / 4, 256, 0, stream>>>(tb, gate_w, rw);

        for (int e0 = 0; e0 < E_EXP; e0 += g) {
            // GEMM1: hb[j] = silu(tb @ w1t[e0+j]^T + b1[e0+j]),  M=T, N=I, K=H
            // grid.x = M-tiles (weight-panel sharers adjacent for T1 swizzle)
            k_gemm8<0><<<dim3(T_TOK / 256, I_DIM / 256, g), 512, 0, stream>>>(
                tb, H_DIM, 0,
                w1t + (size_t)e0 * I_DIM * H_DIM, H_DIM, (long long)I_DIM * H_DIM,
                b1 + (size_t)e0 * I_DIM, I_DIM,
                hb, I_DIM, (long long)T_TOK * I_DIM, H_DIM);
            // GEMM2: eo[j] = hb[j] @ w2t[e0+j]^T  (raw fp32 partials), M=T, N=H, K=I
            k_gemm8<2><<<dim3(T_TOK / 256, H_DIM / 256, g), 512, 0, stream>>>(
                hb, I_DIM, (long long)T_TOK * I_DIM,
                w2t + (size_t)e0 * H_DIM * I_DIM, I_DIM, (long long)H_DIM * I_DIM,
                nullptr, 0,
                eo, H_DIM, (long long)T_TOK * H_DIM, I_DIM);
            // x += sum_j rw[:,e0+j]*(eo[j] + b2[e0+j])
            k_combine<<<T_TOK, 256, 0, stream>>>(eo, rw, b2, x, e0, g);
        }
    }
}

// Round 5
// 2433.081 us; speedup vs baseline: 1.1110x; 1.1110x over previous
//
#include <hip/hip_runtime.h>
#include <hip/hip_bf16.h>

// Problem constants (reference: B=2,S=2048 -> T=4096; H=1024, I=4096, E=8, 2 steps)
#define T_TOK 4096
#define H_DIM 1024
#define I_DIM 4096
#define E_EXP 8
#define RMS_EPS_F 1e-6f

using bf16x8 = __attribute__((ext_vector_type(8))) __bf16;
using f32x4  = __attribute__((ext_vector_type(4))) float;

__device__ inline void gload_lds16(const void* g, void* l) {
    __builtin_amdgcn_global_load_lds(
        (const __attribute__((address_space(1))) void*)g,
        (__attribute__((address_space(3))) void*)l,
        16, 0, 0);
}

// -------- transpose + fp32->bf16 convert: in [R][C] -> out [C][R], batched over blockIdx.z
__global__ __launch_bounds__(256) void k_transpose_cvt(
    const float* __restrict__ in, __hip_bfloat16* __restrict__ out, int R, int C)
{
    __shared__ float tile[32][33];
    const size_t mat = (size_t)R * C;
    in  += (size_t)blockIdx.z * mat;
    out += (size_t)blockIdx.z * mat;
    const int c0 = blockIdx.x * 32, r0 = blockIdx.y * 32;
    const int tx = threadIdx.x & 31, ty = threadIdx.x >> 5;   // 32 x 8
#pragma unroll
    for (int dy = 0; dy < 32; dy += 8)
        tile[ty + dy][tx] = in[(size_t)(r0 + ty + dy) * C + (c0 + tx)];
    __syncthreads();
#pragma unroll
    for (int dy = 0; dy < 32; dy += 8)
        out[(size_t)(c0 + ty + dy) * R + (r0 + tx)] = __float2bfloat16(tile[tx][ty + dy]);
}

// -------- token prep: x [T,H] fp32 -> tb [T,H] bf16, optional rmsnorm*ln_w. 1 block/token.
__global__ __launch_bounds__(256) void k_prep(
    const float* __restrict__ x, const float* __restrict__ lnw,
    __hip_bfloat16* __restrict__ tb, int do_norm)
{
    const int t = blockIdx.x;
    const float* row = x + (size_t)t * H_DIM;
    const int base = threadIdx.x * 4;
    float4 v = *(const float4*)(row + base);
    if (do_norm) {
        float ss = v.x*v.x + v.y*v.y + v.z*v.z + v.w*v.w;
#pragma unroll
        for (int off = 32; off > 0; off >>= 1) ss += __shfl_xor(ss, off);
        __shared__ float wsum[4];
        const int w = threadIdx.x >> 6;
        if ((threadIdx.x & 63) == 0) wsum[w] = ss;
        __syncthreads();
        const float tot = wsum[0] + wsum[1] + wsum[2] + wsum[3];
        const float scale = rsqrtf(tot * (1.0f / H_DIM) + RMS_EPS_F);
        float4 g = *(const float4*)(lnw + base);
        v.x *= scale * g.x; v.y *= scale * g.y; v.z *= scale * g.z; v.w *= scale * g.w;
    }
    __hip_bfloat16* o = tb + (size_t)t * H_DIM + base;
    o[0] = __float2bfloat16(v.x); o[1] = __float2bfloat16(v.y);
    o[2] = __float2bfloat16(v.z); o[3] = __float2bfloat16(v.w);
}

// -------- gate: logits = tb @ gate_w^T, softmax over E=8. One wave per token.
__global__ __launch_bounds__(256) void k_gate(
    const __hip_bfloat16* __restrict__ tb, const float* __restrict__ gw,
    float* __restrict__ rw)
{
    const int t = blockIdx.x * 4 + (threadIdx.x >> 6);
    const int lane = threadIdx.x & 63;
    const __hip_bfloat16* row = tb + (size_t)t * H_DIM;
    float acc[E_EXP];
#pragma unroll
    for (int e = 0; e < E_EXP; ++e) acc[e] = 0.f;
    for (int h = lane; h < H_DIM; h += 64) {
        const float xv = __bfloat162float(row[h]);
#pragma unroll
        for (int e = 0; e < E_EXP; ++e) acc[e] += xv * gw[e * H_DIM + h];
    }
#pragma unroll
    for (int e = 0; e < E_EXP; ++e) {
#pragma unroll
        for (int off = 32; off > 0; off >>= 1) acc[e] += __shfl_xor(acc[e], off);
    }
    if (lane == 0) {
        float mx = acc[0];
#pragma unroll
        for (int e = 1; e < E_EXP; ++e) mx = fmaxf(mx, acc[e]);
        float ex[E_EXP], s = 0.f;
#pragma unroll
        for (int e = 0; e < E_EXP; ++e) { ex[e] = __expf(acc[e] - mx); s += ex[e]; }
        const float inv = 1.f / s;
#pragma unroll
        for (int e = 0; e < E_EXP; ++e) rw[(size_t)t * E_EXP + e] = ex[e] * inv;
    }
}

// ======== 256x256 8-phase GEMM (T2+T3+T4+T5), C = A[M,K] @ Bt[N,K]^T, batched over z.
// 8 waves (2 M x 4 N), per-wave 128x64 = acc[8][4] of 16x16 frags, BK=64.
// Round-5 = round-3 grid/dispatch (x=N-tiles, y=M-tiles, z=expert, NO swizzle —
// round-4's grid swap+XCD swizzle caused 4.4x HBM write amplification, reverted)
// + round-4's register read-ahead (q1..q3 fragments issued under q0's MFMA).
// Stage/barrier/vmcnt ledger identical to round-3 (verified, 3 passing runs).

template<int MB, int NB>
__device__ __forceinline__ void mfma_q(const bf16x8 (&a)[4][2], const bf16x8 (&b)[2][2],
                                       f32x4 (&acc)[8][4]) {
    __builtin_amdgcn_s_setprio(1);
#pragma unroll
    for (int mi = 0; mi < 4; ++mi)
#pragma unroll
        for (int nn = 0; nn < 2; ++nn)
#pragma unroll
            for (int kc = 0; kc < 2; ++kc)
                acc[MB + mi][NB + nn] = __builtin_amdgcn_mfma_f32_16x16x32_bf16(
                    a[mi][kc], b[nn][kc], acc[MB + mi][NB + nn], 0, 0, 0);
    __builtin_amdgcn_s_setprio(0);
}

template<int BB, int MBASE>
__device__ __forceinline__ void ld_a(bf16x8 (&a)[4][2], const char* rdA, int kof0, int kof1) {
#pragma unroll
    for (int mi = 0; mi < 4; ++mi) {
        a[mi][0] = *(const bf16x8*)(rdA + BB * 32768 + (MBASE + mi) * 2048 + kof0);
        a[mi][1] = *(const bf16x8*)(rdA + BB * 32768 + (MBASE + mi) * 2048 + kof1);
    }
}
template<int BB, int NBASE>
__device__ __forceinline__ void ld_b(bf16x8 (&b)[2][2], const char* rdB, int kof0, int kof1) {
#pragma unroll
    for (int ni = 0; ni < 2; ++ni) {
        b[ni][0] = *(const bf16x8*)(rdB + BB * 32768 + (NBASE + ni) * 2048 + kof0);
        b[ni][1] = *(const bf16x8*)(rdB + BB * 32768 + (NBASE + ni) * 2048 + kof1);
    }
}

#define BAR()   __builtin_amdgcn_s_barrier()
#define LGKM0() asm volatile("s_waitcnt lgkmcnt(0)")
#define VMW(n)  asm volatile("s_waitcnt vmcnt(" #n ")" ::: "memory")
#define SCHED0() __builtin_amdgcn_sched_barrier(0)

template <int MODE>
__global__ __launch_bounds__(512, 2) void k_gemm8(
    const __hip_bfloat16* __restrict__ A, int lda, long long strideA,
    const __hip_bfloat16* __restrict__ Bt, int ldb, long long strideB,
    const float* __restrict__ bias, int strideBias,
    void* __restrict__ out, int ldo, long long strideOut, int K)
{
    __shared__ __hip_bfloat16 sA[2][2][128 * 64];   // 64 KB
    __shared__ __hip_bfloat16 sB[2][2][128 * 64];   // 64 KB

    const int z = blockIdx.z;
    A  += (size_t)z * (size_t)strideA;
    Bt += (size_t)z * (size_t)strideB;

    const int tid  = threadIdx.x;
    const int lane = tid & 63;
    const int wid  = tid >> 6;
    const int wr = wid >> 2, wc = wid & 3;          // 2 x 4 waves
    const int m0 = blockIdx.y * 256, n0 = blockIdx.x * 256;

    // ---- staging: dest linear (tid*16); source col pre-swizzled by involution kbyte ^= (row&7)<<4
    const int sr  = tid >> 3;
    const int skb = ((((tid & 7) * 16) ^ ((sr & 7) << 4)) >> 1);
    const __hip_bfloat16* gA = A  + (size_t)(m0 + sr) * lda + skb;
    const __hip_bfloat16* gB = Bt + (size_t)(n0 + sr) * ldb + skb;
    char* const dA = (char*)&sA[0][0][0] + tid * 16;
    char* const dB = (char*)&sB[0][0][0] + tid * 16;

#define STAGE_A(bb, hh, kt) do { \
    const __hip_bfloat16* s_ = gA + (size_t)(hh) * 128 * lda + (size_t)(kt) * 64; \
    gload_lds16(s_,                     dA + (bb) * 32768 + (hh) * 16384); \
    gload_lds16(s_ + (size_t)64 * lda,  dA + (bb) * 32768 + (hh) * 16384 + 8192); \
} while (0)
#define STAGE_B(bb, hh, kt) do { \
    const __hip_bfloat16* s_ = gB + (size_t)(hh) * 128 * ldb + (size_t)(kt) * 64; \
    gload_lds16(s_,                     dB + (bb) * 32768 + (hh) * 16384); \
    gload_lds16(s_ + (size_t)64 * ldb,  dB + (bb) * 32768 + (hh) * 16384 + 8192); \
} while (0)

    // ---- ds_read fragment addressing (swizzled)
    const int fr = lane & 15, kg = lane >> 4;
    const int msk  = (fr & 7) << 4;
    const int kof0 = (kg * 16) ^ msk;
    const int kof1 = (64 + kg * 16) ^ msk;
    const char* rdA = (const char*)&sA[0][wr][0] + fr * 128;
    const char* rdB = (const char*)&sB[0][wc >> 1][0] + (wc & 1) * 8192 + fr * 128;

    f32x4  acc[8][4] = {};
    bf16x8 aL[4][2], aH[4][2], bL[2][2], bH[2][2];

    const int NT = K >> 6;                          // K-tiles of 64 (even, >= 4)

    // ---- prologue: stage T0 (B,A) and T1 (B). 12 issued, VMW(4) lands T0, leaves B(1) in flight.
    STAGE_B(0, 0, 0); STAGE_B(0, 1, 0);
    STAGE_A(0, 0, 0); STAGE_A(0, 1, 0);
    STAGE_B(1, 0, 1); STAGE_B(1, 1, 1);
    VMW(4); BAR(); SCHED0();

    for (int i = 0; i < NT / 2 - 1; ++i) {
        const int t1 = 2 * i + 1;
        // ===== K-tile t0 (buf0); stages: A(t1)->buf1, B(t1+1)->buf0
        ld_a<0, 0>(aL, rdA, kof0, kof1);            // q0 operands (12 reads)
        ld_b<0, 0>(bL, rdB, kof0, kof1);
        STAGE_A(1, 0, t1);
        BAR(); LGKM0();
        ld_b<0, 2>(bH, rdB, kof0, kof1);            // read-ahead under q0 MFMA (12 reads)
        ld_a<0, 4>(aH, rdA, kof0, kof1);
        SCHED0();
        mfma_q<0, 0>(aL, bL, acc);
        BAR();
        STAGE_A(1, 1, t1);
        BAR();
        mfma_q<0, 2>(aL, bH, acc);
        BAR();
        STAGE_B(0, 0, t1 + 1);
        BAR();
        mfma_q<4, 0>(aH, bL, acc);
        BAR();
        STAGE_B(0, 1, t1 + 1);
        BAR();
        mfma_q<4, 2>(aH, bH, acc);
        VMW(4); BAR(); SCHED0();
        // ===== K-tile t1 (buf1); stages: A(t1+1)->buf0, B(t1+2)->buf1
        ld_a<1, 0>(aL, rdA, kof0, kof1);
        ld_b<1, 0>(bL, rdB, kof0, kof1);
        STAGE_A(0, 0, t1 + 1);
        BAR(); LGKM0();
        ld_b<1, 2>(bH, rdB, kof0, kof1);
        ld_a<1, 4>(aH, rdA, kof0, kof1);
        SCHED0();
        mfma_q<0, 0>(aL, bL, acc);
        BAR();
        STAGE_A(0, 1, t1 + 1);
        BAR();
        mfma_q<0, 2>(aL, bH, acc);
        BAR();
        STAGE_B(1, 0, t1 + 2);
        BAR();
        mfma_q<4, 0>(aH, bL, acc);
        BAR();
        STAGE_B(1, 1, t1 + 2);
        BAR();
        mfma_q<4, 2>(aH, bH, acc);
        VMW(4); BAR(); SCHED0();
    }
    {   // ---- last iteration: tiles NT-2 (buf0), NT-1 (buf1); stage only A(NT-1); drain once.
        const int t1 = NT - 1;
        ld_a<0, 0>(aL, rdA, kof0, kof1);
        ld_b<0, 0>(bL, rdB, kof0, kof1);
        STAGE_A(1, 0, t1);
        BAR(); LGKM0();
        ld_b<0, 2>(bH, rdB, kof0, kof1);
        ld_a<0, 4>(aH, rdA, kof0, kof1);
        SCHED0();
        mfma_q<0, 0>(aL, bL, acc);
        BAR();
        STAGE_A(1, 1, t1);
        BAR();
        mfma_q<0, 2>(aL, bH, acc);
        BAR();
        BAR();
        mfma_q<4, 0>(aH, bL, acc);
        BAR();
        mfma_q<4, 2>(aH, bH, acc);
        VMW(0); BAR(); SCHED0();
        ld_a<1, 0>(aL, rdA, kof0, kof1);
        ld_b<1, 0>(bL, rdB, kof0, kof1);
        BAR(); LGKM0();
        ld_b<1, 2>(bH, rdB, kof0, kof1);
        ld_a<1, 4>(aH, rdA, kof0, kof1);
        SCHED0();
        mfma_q<0, 0>(aL, bL, acc);
        mfma_q<0, 2>(aL, bH, acc);
        mfma_q<4, 0>(aH, bL, acc);
        mfma_q<4, 2>(aH, bH, acc);
    }

    // ---- epilogue. C-frag layout: col = lane&15 (fr), row = kg*4 + j  [m89-verified]
    const int rB = kg * 4;
    if (MODE == 0) {
        __hip_bfloat16* O = (__hip_bfloat16*)out + (size_t)z * (size_t)strideOut;
        const float* bz = bias + (size_t)z * (size_t)strideBias;
#pragma unroll
        for (int mi = 0; mi < 8; ++mi) {
            const int gm = m0 + wr * 128 + mi * 16 + rB;
#pragma unroll
            for (int ni = 0; ni < 4; ++ni) {
                const int gn = n0 + wc * 64 + ni * 16 + fr;
                const float bv = bz[gn];
#pragma unroll
                for (int j = 0; j < 4; ++j) {
                    float v = acc[mi][ni][j] + bv;
                    v = v / (1.f + __expf(-v));        // silu
                    O[(size_t)(gm + j) * ldo + gn] = __float2bfloat16(v);
                }
            }
        }
    } else {
        float* O = (float*)out + (size_t)z * (size_t)strideOut;
#pragma unroll
        for (int mi = 0; mi < 8; ++mi) {
            const int gm = m0 + wr * 128 + mi * 16 + rB;
#pragma unroll
            for (int ni = 0; ni < 4; ++ni) {
                const int gn = n0 + wc * 64 + ni * 16 + fr;
#pragma unroll
                for (int j = 0; j < 4; ++j)
                    O[(size_t)(gm + j) * ldo + gn] = acc[mi][ni][j];
            }
        }
    }
#undef STAGE_A
#undef STAGE_B
}

// -------- combine: x[t,h] += sum_j rw[t,e0+j]*(eo[j][t][h] + b2[e0+j][h]). 1 block/token.
__global__ __launch_bounds__(256) void k_combine(
    const float* __restrict__ eo, const float* __restrict__ rw,
    const float* __restrict__ b2, float* __restrict__ x, int e0, int g)
{
    const int t = blockIdx.x;
    const int h = threadIdx.x * 4;
    float4 acc = *(const float4*)(x + (size_t)t * H_DIM + h);
    for (int j = 0; j < g; ++j) {
        const float w = rw[(size_t)t * E_EXP + e0 + j];
        const float4 v  = *(const float4*)(eo + ((size_t)j * T_TOK + t) * H_DIM + h);
        const float4 bz = *(const float4*)(b2 + (size_t)(e0 + j) * H_DIM + h);
        acc.x += w * (v.x + bz.x);
        acc.y += w * (v.y + bz.y);
        acc.z += w * (v.z + bz.z);
        acc.w += w * (v.w + bz.w);
    }
    *(float4*)(x + (size_t)t * H_DIM + h) = acc;
}

extern "C" void kernel_launch(void* const* d_in, const int* in_sizes, int n_in,
                              void* d_out, int out_size, void* d_ws, size_t ws_size,
                              hipStream_t stream)
{
    const float* hidden = (const float*)d_in[0];
    const float* gate_w = (const float*)d_in[1];
    const float* w1     = (const float*)d_in[2];
    const float* b1     = (const float*)d_in[3];
    const float* w2     = (const float*)d_in[4];
    const float* b2     = (const float*)d_in[5];
    const float* ln_w   = (const float*)d_in[6];
    float* x = (float*)d_out;

    // workspace carve
    const size_t w1t_b = (size_t)E_EXP * I_DIM * H_DIM * 2;   // 64 MB
    const size_t w2t_b = (size_t)E_EXP * H_DIM * I_DIM * 2;   // 64 MB
    const size_t tb_b  = (size_t)T_TOK * H_DIM * 2;           //  8 MB
    const size_t rw_b  = (size_t)T_TOK * E_EXP * 4;           // 128 KB
    const size_t hb1_b = (size_t)T_TOK * I_DIM * 2;           // 32 MB per expert
    const size_t eo1_b = (size_t)T_TOK * H_DIM * 4;           // 16 MB per expert
    const size_t base_b = w1t_b + w2t_b + tb_b + rw_b;

    // largest expert group that fits
    int g = 0;
    for (int cand = 8; cand >= 1; cand >>= 1)
        if (base_b + (size_t)cand * (hb1_b + eo1_b) <= ws_size) { g = cand; break; }

    char* ws = (char*)d_ws;
    __hip_bfloat16* w1t = (__hip_bfloat16*)ws;  ws += w1t_b;
    __hip_bfloat16* w2t = (__hip_bfloat16*)ws;  ws += w2t_b;
    __hip_bfloat16* tb  = (__hip_bfloat16*)ws;  ws += tb_b;
    float*          rw  = (float*)ws;           ws += rw_b;
    __hip_bfloat16* hb  = (__hip_bfloat16*)ws;
    float*          eo  = (float*)(ws + (size_t)(g > 0 ? g : 1) * hb1_b);

    // x = hidden_states (running residual lives in d_out)
    hipMemcpyAsync(x, hidden, (size_t)T_TOK * H_DIM * 4, hipMemcpyDeviceToDevice, stream);

    if (g == 0) return;  // ws too small (harness has given >= 232 MB so far)

    // bf16 weights in B^T layout: w1t [E][I][H], w2t [E][H][I]
    k_transpose_cvt<<<dim3(I_DIM / 32, H_DIM / 32, E_EXP), 256, 0, stream>>>(w1, w1t, H_DIM, I_DIM);
    k_transpose_cvt<<<dim3(H_DIM / 32, I_DIM / 32, E_EXP), 256, 0, stream>>>(w2, w2t, I_DIM, H_DIM);

    for (int step = 0; step < 2; ++step) {
        k_prep<<<T_TOK, 256, 0, stream>>>(x, ln_w, tb, step);
        k_gate<<<T_TOK / 4, 256, 0, stream>>>(tb, gate_w, rw);

        for (int e0 = 0; e0 < E_EXP; e0 += g) {
            // GEMM1: hb[j] = silu(tb @ w1t[e0+j]^T + b1[e0+j]),  M=T, N=I, K=H
            k_gemm8<0><<<dim3(I_DIM / 256, T_TOK / 256, g), 512, 0, stream>>>(
                tb, H_DIM, 0,
                w1t + (size_t)e0 * I_DIM * H_DIM, H_DIM, (long long)I_DIM * H_DIM,
                b1 + (size_t)e0 * I_DIM, I_DIM,
                hb, I_DIM, (long long)T_TOK * I_DIM, H_DIM);
            // GEMM2: eo[j] = hb[j] @ w2t[e0+j]^T  (raw fp32 partials), M=T, N=H, K=I
            k_gemm8<2><<<dim3(H_DIM / 256, T_TOK / 256, g), 512, 0, stream>>>(
                hb, I_DIM, (long long)T_TOK * I_DIM,
                w2t + (size_t)e0 * H_DIM * I_DIM, I_DIM, (long long)H_DIM * I_DIM,
                nullptr, 0,
                eo, H_DIM, (long long)T_TOK * H_DIM, I_DIM);
            // x += sum_j rw[:,e0+j]*(eo[j] + b2[e0+j])
            k_combine<<<T_TOK, 256, 0, stream>>>(eo, rw, b2, x, e0, g);
        }
    }
}

// Round 6
// 1496.499 us; speedup vs baseline: 1.8064x; 1.6258x over previous
//
#include <hip/hip_runtime.h>
#include <hip/hip_bf16.h>

// Problem constants (reference: B=2,S=2048 -> T=4096; H=1024, I=4096, E=8, 2 steps)
#define T_TOK 4096
#define H_DIM 1024
#define I_DIM 4096
#define E_EXP 8
#define RMS_EPS_F 1e-6f

using bf16x8 = __attribute__((ext_vector_type(8))) __bf16;
using f32x4  = __attribute__((ext_vector_type(4))) float;

__device__ inline void gload_lds16(const void* g, void* l) {
    __builtin_amdgcn_global_load_lds(
        (const __attribute__((address_space(1))) void*)g,
        (__attribute__((address_space(3))) void*)l,
        16, 0, 0);
}

// -------- transpose + fp32->bf16 convert: in [R][C] -> out [C][R], batched over blockIdx.z
__global__ __launch_bounds__(256) void k_transpose_cvt(
    const float* __restrict__ in, __hip_bfloat16* __restrict__ out, int R, int C)
{
    __shared__ float tile[32][33];
    const size_t mat = (size_t)R * C;
    in  += (size_t)blockIdx.z * mat;
    out += (size_t)blockIdx.z * mat;
    const int c0 = blockIdx.x * 32, r0 = blockIdx.y * 32;
    const int tx = threadIdx.x & 31, ty = threadIdx.x >> 5;   // 32 x 8
#pragma unroll
    for (int dy = 0; dy < 32; dy += 8)
        tile[ty + dy][tx] = in[(size_t)(r0 + ty + dy) * C + (c0 + tx)];
    __syncthreads();
#pragma unroll
    for (int dy = 0; dy < 32; dy += 8)
        out[(size_t)(c0 + ty + dy) * R + (r0 + tx)] = __float2bfloat16(tile[tx][ty + dy]);
}

// -------- token prep: x [T,H] fp32 -> tb [T,H] bf16, optional rmsnorm*ln_w. 1 block/token.
__global__ __launch_bounds__(256) void k_prep(
    const float* __restrict__ x, const float* __restrict__ lnw,
    __hip_bfloat16* __restrict__ tb, int do_norm)
{
    const int t = blockIdx.x;
    const float* row = x + (size_t)t * H_DIM;
    const int base = threadIdx.x * 4;
    float4 v = *(const float4*)(row + base);
    if (do_norm) {
        float ss = v.x*v.x + v.y*v.y + v.z*v.z + v.w*v.w;
#pragma unroll
        for (int off = 32; off > 0; off >>= 1) ss += __shfl_xor(ss, off);
        __shared__ float wsum[4];
        const int w = threadIdx.x >> 6;
        if ((threadIdx.x & 63) == 0) wsum[w] = ss;
        __syncthreads();
        const float tot = wsum[0] + wsum[1] + wsum[2] + wsum[3];
        const float scale = rsqrtf(tot * (1.0f / H_DIM) + RMS_EPS_F);
        float4 g = *(const float4*)(lnw + base);
        v.x *= scale * g.x; v.y *= scale * g.y; v.z *= scale * g.z; v.w *= scale * g.w;
    }
    __hip_bfloat16* o = tb + (size_t)t * H_DIM + base;
    o[0] = __float2bfloat16(v.x); o[1] = __float2bfloat16(v.y);
    o[2] = __float2bfloat16(v.z); o[3] = __float2bfloat16(v.w);
}

// -------- gate: logits = tb @ gate_w^T, softmax over E=8. One wave per token.
__global__ __launch_bounds__(256) void k_gate(
    const __hip_bfloat16* __restrict__ tb, const float* __restrict__ gw,
    float* __restrict__ rw)
{
    const int t = blockIdx.x * 4 + (threadIdx.x >> 6);
    const int lane = threadIdx.x & 63;
    const __hip_bfloat16* row = tb + (size_t)t * H_DIM;
    float acc[E_EXP];
#pragma unroll
    for (int e = 0; e < E_EXP; ++e) acc[e] = 0.f;
    for (int h = lane; h < H_DIM; h += 64) {
        const float xv = __bfloat162float(row[h]);
#pragma unroll
        for (int e = 0; e < E_EXP; ++e) acc[e] += xv * gw[e * H_DIM + h];
    }
#pragma unroll
    for (int e = 0; e < E_EXP; ++e) {
#pragma unroll
        for (int off = 32; off > 0; off >>= 1) acc[e] += __shfl_xor(acc[e], off);
    }
    if (lane == 0) {
        float mx = acc[0];
#pragma unroll
        for (int e = 1; e < E_EXP; ++e) mx = fmaxf(mx, acc[e]);
        float ex[E_EXP], s = 0.f;
#pragma unroll
        for (int e = 0; e < E_EXP; ++e) { ex[e] = __expf(acc[e] - mx); s += ex[e]; }
        const float inv = 1.f / s;
#pragma unroll
        for (int e = 0; e < E_EXP; ++e) rw[(size_t)t * E_EXP + e] = ex[e] * inv;
    }
}

// ======== 256x256 8-phase GEMM (T2+T3+T4+T5), C = A[M,K] @ Bt[N,K]^T, batched over z.
// 8 waves (2 M x 4 N), per-wave 128x64 = acc[8][4] of 16x16 frags, BK=64.
// Round-6: round-3 base (NO read-ahead — it caused scratch spills, W 132->413MB;
// NO grid swizzle) with phases re-cut along (m-half x kc) so per-phase ds_reads
// are 8/4/8/4 (was 12/4/8/0). Same total LDS traffic, shorter operand lifetimes.
// Stage slots: A(t+1)->other buf at p0/p1; BOTH B(t+2) halves at p3 (B buf is
// read through p2 under this cut). vmcnt ledger re-verified: steady-state
// VMW(4) completes exactly next tile's {A,B}, leaves next B x4 in flight.

template<int BB, int MBASE>
__device__ __forceinline__ void ld_a4(bf16x8 (&a)[4], const char* rdA, int kof) {
#pragma unroll
    for (int mi = 0; mi < 4; ++mi)
        a[mi] = *(const bf16x8*)(rdA + BB * 32768 + (MBASE + mi) * 2048 + kof);
}
template<int BB>
__device__ __forceinline__ void ld_b4(bf16x8 (&b)[4], const char* rdB, int kof) {
#pragma unroll
    for (int ni = 0; ni < 4; ++ni)
        b[ni] = *(const bf16x8*)(rdB + BB * 32768 + ni * 2048 + kof);
}
template<int MB>
__device__ __forceinline__ void mfma_cell(const bf16x8 (&a)[4], const bf16x8 (&b)[4],
                                          f32x4 (&acc)[8][4]) {
    __builtin_amdgcn_s_setprio(1);
#pragma unroll
    for (int mi = 0; mi < 4; ++mi)
#pragma unroll
        for (int ni = 0; ni < 4; ++ni)
            acc[MB + mi][ni] = __builtin_amdgcn_mfma_f32_16x16x32_bf16(
                a[mi], b[ni], acc[MB + mi][ni], 0, 0, 0);
    __builtin_amdgcn_s_setprio(0);
}

#define BAR()   __builtin_amdgcn_s_barrier()
#define LGKM0() asm volatile("s_waitcnt lgkmcnt(0)")
#define VMW(n)  asm volatile("s_waitcnt vmcnt(" #n ")" ::: "memory")
#define SCHED0() __builtin_amdgcn_sched_barrier(0)

template <int MODE>
__global__ __launch_bounds__(512, 2) void k_gemm8(
    const __hip_bfloat16* __restrict__ A, int lda, long long strideA,
    const __hip_bfloat16* __restrict__ Bt, int ldb, long long strideB,
    const float* __restrict__ bias, int strideBias,
    void* __restrict__ out, int ldo, long long strideOut, int K)
{
    __shared__ __hip_bfloat16 sA[2][2][128 * 64];   // 64 KB
    __shared__ __hip_bfloat16 sB[2][2][128 * 64];   // 64 KB

    const int z = blockIdx.z;
    A  += (size_t)z * (size_t)strideA;
    Bt += (size_t)z * (size_t)strideB;

    const int tid  = threadIdx.x;
    const int lane = tid & 63;
    const int wid  = tid >> 6;
    const int wr = wid >> 2, wc = wid & 3;          // 2 x 4 waves
    const int m0 = blockIdx.y * 256, n0 = blockIdx.x * 256;

    // ---- staging: dest linear (tid*16); source col pre-swizzled by involution kbyte ^= (row&7)<<4
    const int sr  = tid >> 3;
    const int skb = ((((tid & 7) * 16) ^ ((sr & 7) << 4)) >> 1);
    const __hip_bfloat16* gA = A  + (size_t)(m0 + sr) * lda + skb;
    const __hip_bfloat16* gB = Bt + (size_t)(n0 + sr) * ldb + skb;
    char* const dA = (char*)&sA[0][0][0] + tid * 16;
    char* const dB = (char*)&sB[0][0][0] + tid * 16;

#define STAGE_A(bb, hh, kt) do { \
    const __hip_bfloat16* s_ = gA + (size_t)(hh) * 128 * lda + (size_t)(kt) * 64; \
    gload_lds16(s_,                     dA + (bb) * 32768 + (hh) * 16384); \
    gload_lds16(s_ + (size_t)64 * lda,  dA + (bb) * 32768 + (hh) * 16384 + 8192); \
} while (0)
#define STAGE_B(bb, hh, kt) do { \
    const __hip_bfloat16* s_ = gB + (size_t)(hh) * 128 * ldb + (size_t)(kt) * 64; \
    gload_lds16(s_,                     dB + (bb) * 32768 + (hh) * 16384); \
    gload_lds16(s_ + (size_t)64 * ldb,  dB + (bb) * 32768 + (hh) * 16384 + 8192); \
} while (0)

    // ---- ds_read fragment addressing (swizzled)
    const int fr = lane & 15, kg = lane >> 4;
    const int msk  = (fr & 7) << 4;
    const int kof0 = (kg * 16) ^ msk;               // kc=0 byte offset
    const int kof1 = (64 + kg * 16) ^ msk;          // kc=1
    const char* rdA = (const char*)&sA[0][wr][0] + fr * 128;
    const char* rdB = (const char*)&sB[0][wc >> 1][0] + (wc & 1) * 8192 + fr * 128;

    f32x4  acc[8][4] = {};
    bf16x8 a[4], a2[4], b[4];

    const int NT = K >> 6;                          // K-tiles of 64 (even, >= 4)

    // ---- prologue: stage T0 (B,A) and T1 (B). 12 issued, VMW(4) lands T0, leaves B(1) in flight.
    STAGE_B(0, 0, 0); STAGE_B(0, 1, 0);
    STAGE_A(0, 0, 0); STAGE_A(0, 1, 0);
    STAGE_B(1, 0, 1); STAGE_B(1, 1, 1);
    VMW(4); BAR(); SCHED0();

    for (int i = 0; i < NT / 2 - 1; ++i) {
        const int t1 = 2 * i + 1;
        // ===== K-tile t0 (buf0); stages: A(t1)->buf1 @p0/p1, B(t1+1)->buf0 @p3
        ld_a4<0, 0>(a, rdA, kof0);                  // p0 (h0,kc0): 8 reads
        ld_b4<0>(b, rdB, kof0);
        STAGE_A(1, 0, t1);
        BAR(); LGKM0();
        mfma_cell<0>(a, b, acc);
        BAR();
        ld_a4<0, 4>(a2, rdA, kof0);                 // p1 (h1,kc0): 4 reads
        STAGE_A(1, 1, t1);
        BAR(); LGKM0();
        mfma_cell<4>(a2, b, acc);
        BAR();
        ld_a4<0, 4>(a2, rdA, kof1);                 // p2 (h1,kc1): 8 reads
        ld_b4<0>(b, rdB, kof1);
        BAR(); LGKM0();
        mfma_cell<4>(a2, b, acc);
        BAR();
        ld_a4<0, 0>(a, rdA, kof1);                  // p3 (h0,kc1): 4 reads
        STAGE_B(0, 0, t1 + 1); STAGE_B(0, 1, t1 + 1);
        BAR(); LGKM0();
        mfma_cell<0>(a, b, acc);
        VMW(4); BAR(); SCHED0();
        // ===== K-tile t1 (buf1); stages: A(t1+1)->buf0 @p0/p1, B(t1+2)->buf1 @p3
        ld_a4<1, 0>(a, rdA, kof0);
        ld_b4<1>(b, rdB, kof0);
        STAGE_A(0, 0, t1 + 1);
        BAR(); LGKM0();
        mfma_cell<0>(a, b, acc);
        BAR();
        ld_a4<1, 4>(a2, rdA, kof0);
        STAGE_A(0, 1, t1 + 1);
        BAR(); LGKM0();
        mfma_cell<4>(a2, b, acc);
        BAR();
        ld_a4<1, 4>(a2, rdA, kof1);
        ld_b4<1>(b, rdB, kof1);
        BAR(); LGKM0();
        mfma_cell<4>(a2, b, acc);
        BAR();
        ld_a4<1, 0>(a, rdA, kof1);
        STAGE_B(1, 0, t1 + 2); STAGE_B(1, 1, t1 + 2);
        BAR(); LGKM0();
        mfma_cell<0>(a, b, acc);
        VMW(4); BAR(); SCHED0();
    }
    {   // ---- tail: tiles NT-2 (buf0: stage only A(NT-1), drain all), NT-1 (buf1: no stages)
        const int t1 = NT - 1;
        ld_a4<0, 0>(a, rdA, kof0);
        ld_b4<0>(b, rdB, kof0);
        STAGE_A(1, 0, t1);
        BAR(); LGKM0();
        mfma_cell<0>(a, b, acc);
        BAR();
        ld_a4<0, 4>(a2, rdA, kof0);
        STAGE_A(1, 1, t1);
        BAR(); LGKM0();
        mfma_cell<4>(a2, b, acc);
        BAR();
        ld_a4<0, 4>(a2, rdA, kof1);
        ld_b4<0>(b, rdB, kof1);
        BAR(); LGKM0();
        mfma_cell<4>(a2, b, acc);
        BAR();
        ld_a4<0, 0>(a, rdA, kof1);
        BAR(); LGKM0();
        mfma_cell<0>(a, b, acc);
        VMW(0); BAR(); SCHED0();
        // tile NT-1 (buf1)
        ld_a4<1, 0>(a, rdA, kof0);
        ld_b4<1>(b, rdB, kof0);
        BAR(); LGKM0();
        mfma_cell<0>(a, b, acc);
        BAR();
        ld_a4<1, 4>(a2, rdA, kof0);
        BAR(); LGKM0();
        mfma_cell<4>(a2, b, acc);
        BAR();
        ld_a4<1, 4>(a2, rdA, kof1);
        ld_b4<1>(b, rdB, kof1);
        BAR(); LGKM0();
        mfma_cell<4>(a2, b, acc);
        BAR();
        ld_a4<1, 0>(a, rdA, kof1);
        BAR(); LGKM0();
        mfma_cell<0>(a, b, acc);
    }

    // ---- epilogue. C-frag layout: col = lane&15 (fr), row = kg*4 + j  [m89-verified]
    const int rB = kg * 4;
    if (MODE == 0) {
        __hip_bfloat16* O = (__hip_bfloat16*)out + (size_t)z * (size_t)strideOut;
        const float* bz = bias + (size_t)z * (size_t)strideBias;
#pragma unroll
        for (int mi = 0; mi < 8; ++mi) {
            const int gm = m0 + wr * 128 + mi * 16 + rB;
#pragma unroll
            for (int ni = 0; ni < 4; ++ni) {
                const int gn = n0 + wc * 64 + ni * 16 + fr;
                const float bv = bz[gn];
#pragma unroll
                for (int j = 0; j < 4; ++j) {
                    float v = acc[mi][ni][j] + bv;
                    v = v / (1.f + __expf(-v));        // silu
                    O[(size_t)(gm + j) * ldo + gn] = __float2bfloat16(v);
                }
            }
        }
    } else {
        float* O = (float*)out + (size_t)z * (size_t)strideOut;
#pragma unroll
        for (int mi = 0; mi < 8; ++mi) {
            const int gm = m0 + wr * 128 + mi * 16 + rB;
#pragma unroll
            for (int ni = 0; ni < 4; ++ni) {
                const int gn = n0 + wc * 64 + ni * 16 + fr;
#pragma unroll
                for (int j = 0; j < 4; ++j)
                    O[(size_t)(gm + j) * ldo + gn] = acc[mi][ni][j];
            }
        }
    }
#undef STAGE_A
#undef STAGE_B
}

// -------- combine: x[t,h] += sum_j rw[t,e0+j]*(eo[j][t][h] + b2[e0+j][h]). 1 block/token.
__global__ __launch_bounds__(256) void k_combine(
    const float* __restrict__ eo, const float* __restrict__ rw,
    const float* __restrict__ b2, float* __restrict__ x, int e0, int g)
{
    const int t = blockIdx.x;
    const int h = threadIdx.x * 4;
    float4 acc = *(const float4*)(x + (size_t)t * H_DIM + h);
    for (int j = 0; j < g; ++j) {
        const float w = rw[(size_t)t * E_EXP + e0 + j];
        const float4 v  = *(const float4*)(eo + ((size_t)j * T_TOK + t) * H_DIM + h);
        const float4 bz = *(const float4*)(b2 + (size_t)(e0 + j) * H_DIM + h);
        acc.x += w * (v.x + bz.x);
        acc.y += w * (v.y + bz.y);
        acc.z += w * (v.z + bz.z);
        acc.w += w * (v.w + bz.w);
    }
    *(float4*)(x + (size_t)t * H_DIM + h) = acc;
}

extern "C" void kernel_launch(void* const* d_in, const int* in_sizes, int n_in,
                              void* d_out, int out_size, void* d_ws, size_t ws_size,
                              hipStream_t stream)
{
    const float* hidden = (const float*)d_in[0];
    const float* gate_w = (const float*)d_in[1];
    const float* w1     = (const float*)d_in[2];
    const float* b1     = (const float*)d_in[3];
    const float* w2     = (const float*)d_in[4];
    const float* b2     = (const float*)d_in[5];
    const float* ln_w   = (const float*)d_in[6];
    float* x = (float*)d_out;

    // workspace carve
    const size_t w1t_b = (size_t)E_EXP * I_DIM * H_DIM * 2;   // 64 MB
    const size_t w2t_b = (size_t)E_EXP * H_DIM * I_DIM * 2;   // 64 MB
    const size_t tb_b  = (size_t)T_TOK * H_DIM * 2;           //  8 MB
    const size_t rw_b  = (size_t)T_TOK * E_EXP * 4;           // 128 KB
    const size_t hb1_b = (size_t)T_TOK * I_DIM * 2;           // 32 MB per expert
    const size_t eo1_b = (size_t)T_TOK * H_DIM * 4;           // 16 MB per expert
    const size_t base_b = w1t_b + w2t_b + tb_b + rw_b;

    // largest expert group that fits
    int g = 0;
    for (int cand = 8; cand >= 1; cand >>= 1)
        if (base_b + (size_t)cand * (hb1_b + eo1_b) <= ws_size) { g = cand; break; }

    char* ws = (char*)d_ws;
    __hip_bfloat16* w1t = (__hip_bfloat16*)ws;  ws += w1t_b;
    __hip_bfloat16* w2t = (__hip_bfloat16*)ws;  ws += w2t_b;
    __hip_bfloat16* tb  = (__hip_bfloat16*)ws;  ws += tb_b;
    float*          rw  = (float*)ws;           ws += rw_b;
    __hip_bfloat16* hb  = (__hip_bfloat16*)ws;
    float*          eo  = (float*)(ws + (size_t)(g > 0 ? g : 1) * hb1_b);

    // x = hidden_states (running residual lives in d_out)
    hipMemcpyAsync(x, hidden, (size_t)T_TOK * H_DIM * 4, hipMemcpyDeviceToDevice, stream);

    if (g == 0) return;  // ws too small (harness has given >= 232 MB so far)

    // bf16 weights in B^T layout: w1t [E][I][H], w2t [E][H][I]
    k_transpose_cvt<<<dim3(I_DIM / 32, H_DIM / 32, E_EXP), 256, 0, stream>>>(w1, w1t, H_DIM, I_DIM);
    k_transpose_cvt<<<dim3(H_DIM / 32, I_DIM / 32, E_EXP), 256, 0, stream>>>(w2, w2t, I_DIM, H_DIM);

    for (int step = 0; step < 2; ++step) {
        k_prep<<<T_TOK, 256, 0, stream>>>(x, ln_w, tb, step);
        k_gate<<<T_TOK / 4, 256, 0, stream>>>(tb, gate_w, rw);

        for (int e0 = 0; e0 < E_EXP; e0 += g) {
            // GEMM1: hb[j] = silu(tb @ w1t[e0+j]^T + b1[e0+j]),  M=T, N=I, K=H
            k_gemm8<0><<<dim3(I_DIM / 256, T_TOK / 256, g), 512, 0, stream>>>(
                tb, H_DIM, 0,
                w1t + (size_t)e0 * I_DIM * H_DIM, H_DIM, (long long)I_DIM * H_DIM,
                b1 + (size_t)e0 * I_DIM, I_DIM,
                hb, I_DIM, (long long)T_TOK * I_DIM, H_DIM);
            // GEMM2: eo[j] = hb[j] @ w2t[e0+j]^T  (raw fp32 partials), M=T, N=H, K=I
            k_gemm8<2><<<dim3(H_DIM / 256, T_TOK / 256, g), 512, 0, stream>>>(
                hb, I_DIM, (long long)T_TOK * I_DIM,
                w2t + (size_t)e0 * H_DIM * I_DIM, I_DIM, (long long)H_DIM * I_DIM,
                nullptr, 0,
                eo, H_DIM, (long long)T_TOK * H_DIM, I_DIM);
            // x += sum_j rw[:,e0+j]*(eo[j] + b2[e0+j])
            k_combine<<<T_TOK, 256, 0, stream>>>(eo, rw, b2, x, e0, g);
        }
    }
}

// Round 7
// 1420.898 us; speedup vs baseline: 1.9025x; 1.0532x over previous
//
#include <hip/hip_runtime.h>
#include <hip/hip_bf16.h>

// Problem constants (reference: B=2,S=2048 -> T=4096; H=1024, I=4096, E=8, 2 steps)
#define T_TOK 4096
#define H_DIM 1024
#define I_DIM 4096
#define E_EXP 8
#define RMS_EPS_F 1e-6f

using bf16x8 = __attribute__((ext_vector_type(8))) __bf16;
using f32x4  = __attribute__((ext_vector_type(4))) float;

__device__ inline void gload_lds16(const void* g, void* l) {
    __builtin_amdgcn_global_load_lds(
        (const __attribute__((address_space(1))) void*)g,
        (__attribute__((address_space(3))) void*)l,
        16, 0, 0);
}

// -------- transpose + fp32->bf16 convert: in [R][C] -> out [C][R], batched over blockIdx.z
__global__ __launch_bounds__(256) void k_transpose_cvt(
    const float* __restrict__ in, __hip_bfloat16* __restrict__ out, int R, int C)
{
    __shared__ float tile[32][33];
    const size_t mat = (size_t)R * C;
    in  += (size_t)blockIdx.z * mat;
    out += (size_t)blockIdx.z * mat;
    const int c0 = blockIdx.x * 32, r0 = blockIdx.y * 32;
    const int tx = threadIdx.x & 31, ty = threadIdx.x >> 5;   // 32 x 8
#pragma unroll
    for (int dy = 0; dy < 32; dy += 8)
        tile[ty + dy][tx] = in[(size_t)(r0 + ty + dy) * C + (c0 + tx)];
    __syncthreads();
#pragma unroll
    for (int dy = 0; dy < 32; dy += 8)
        out[(size_t)(c0 + ty + dy) * R + (r0 + tx)] = __float2bfloat16(tile[tx][ty + dy]);
}

// -------- token prep: x [T,H] fp32 -> tb [T,H] bf16, optional rmsnorm*ln_w. 1 block/token.
__global__ __launch_bounds__(256) void k_prep(
    const float* __restrict__ x, const float* __restrict__ lnw,
    __hip_bfloat16* __restrict__ tb, int do_norm)
{
    const int t = blockIdx.x;
    const float* row = x + (size_t)t * H_DIM;
    const int base = threadIdx.x * 4;
    float4 v = *(const float4*)(row + base);
    if (do_norm) {
        float ss = v.x*v.x + v.y*v.y + v.z*v.z + v.w*v.w;
#pragma unroll
        for (int off = 32; off > 0; off >>= 1) ss += __shfl_xor(ss, off);
        __shared__ float wsum[4];
        const int w = threadIdx.x >> 6;
        if ((threadIdx.x & 63) == 0) wsum[w] = ss;
        __syncthreads();
        const float tot = wsum[0] + wsum[1] + wsum[2] + wsum[3];
        const float scale = rsqrtf(tot * (1.0f / H_DIM) + RMS_EPS_F);
        float4 g = *(const float4*)(lnw + base);
        v.x *= scale * g.x; v.y *= scale * g.y; v.z *= scale * g.z; v.w *= scale * g.w;
    }
    __hip_bfloat16* o = tb + (size_t)t * H_DIM + base;
    o[0] = __float2bfloat16(v.x); o[1] = __float2bfloat16(v.y);
    o[2] = __float2bfloat16(v.z); o[3] = __float2bfloat16(v.w);
}

// -------- gate: logits = tb @ gate_w^T, softmax over E=8. One wave per token.
__global__ __launch_bounds__(256) void k_gate(
    const __hip_bfloat16* __restrict__ tb, const float* __restrict__ gw,
    float* __restrict__ rw)
{
    const int t = blockIdx.x * 4 + (threadIdx.x >> 6);
    const int lane = threadIdx.x & 63;
    const __hip_bfloat16* row = tb + (size_t)t * H_DIM;
    float acc[E_EXP];
#pragma unroll
    for (int e = 0; e < E_EXP; ++e) acc[e] = 0.f;
    for (int h = lane; h < H_DIM; h += 64) {
        const float xv = __bfloat162float(row[h]);
#pragma unroll
        for (int e = 0; e < E_EXP; ++e) acc[e] += xv * gw[e * H_DIM + h];
    }
#pragma unroll
    for (int e = 0; e < E_EXP; ++e) {
#pragma unroll
        for (int off = 32; off > 0; off >>= 1) acc[e] += __shfl_xor(acc[e], off);
    }
    if (lane == 0) {
        float mx = acc[0];
#pragma unroll
        for (int e = 1; e < E_EXP; ++e) mx = fmaxf(mx, acc[e]);
        float ex[E_EXP], s = 0.f;
#pragma unroll
        for (int e = 0; e < E_EXP; ++e) { ex[e] = __expf(acc[e] - mx); s += ex[e]; }
        const float inv = 1.f / s;
#pragma unroll
        for (int e = 0; e < E_EXP; ++e) rw[(size_t)t * E_EXP + e] = ex[e] * inv;
    }
}

// ======== 256x256 8-phase GEMM (T2+T3+T4+T5), C = A[M,K] @ Bt[N,K]^T, batched over z.
// 8 waves (2 M x 4 N), per-wave 128x64 = acc[8][4] of 16x16 frags, BK=64.
// Round-7 = round-3's EXACT memory-op ledger (quadrant phase cut, same stage
// slots, same VMW(4) placement — 3x verified race-free) + scheduler pins:
//   - sched_barrier(0) after each phase's issue group (reads+stages stay ABOVE
//     the barrier; raw s_barrier is NOT a memory fence, compiler was sinking
//     the ds_reads to their uses, serializing LDS with MFMA)
//   - lgkmcnt(0) with "memory" clobber + sched_barrier(0) before each MFMA
//     cluster (rule #18)
//   - lgkmcnt(8) throttle in the 12-read phase (m201 template)

template<int MB, int NB>
__device__ __forceinline__ void mfma_q(const bf16x8 (&a)[4][2], const bf16x8 (&b)[2][2],
                                       f32x4 (&acc)[8][4]) {
    __builtin_amdgcn_s_setprio(1);
#pragma unroll
    for (int mi = 0; mi < 4; ++mi)
#pragma unroll
        for (int nn = 0; nn < 2; ++nn)
#pragma unroll
            for (int kc = 0; kc < 2; ++kc)
                acc[MB + mi][NB + nn] = __builtin_amdgcn_mfma_f32_16x16x32_bf16(
                    a[mi][kc], b[nn][kc], acc[MB + mi][NB + nn], 0, 0, 0);
    __builtin_amdgcn_s_setprio(0);
}

template<int BB, int MBASE>
__device__ __forceinline__ void ld_a(bf16x8 (&a)[4][2], const char* rdA, int kof0, int kof1) {
#pragma unroll
    for (int mi = 0; mi < 4; ++mi) {
        a[mi][0] = *(const bf16x8*)(rdA + BB * 32768 + (MBASE + mi) * 2048 + kof0);
        a[mi][1] = *(const bf16x8*)(rdA + BB * 32768 + (MBASE + mi) * 2048 + kof1);
    }
}
template<int BB, int NBASE>
__device__ __forceinline__ void ld_b(bf16x8 (&b)[2][2], const char* rdB, int kof0, int kof1) {
#pragma unroll
    for (int ni = 0; ni < 2; ++ni) {
        b[ni][0] = *(const bf16x8*)(rdB + BB * 32768 + (NBASE + ni) * 2048 + kof0);
        b[ni][1] = *(const bf16x8*)(rdB + BB * 32768 + (NBASE + ni) * 2048 + kof1);
    }
}

#define BAR()   __builtin_amdgcn_s_barrier()
#define LGKM0() asm volatile("s_waitcnt lgkmcnt(0)" ::: "memory")
#define LGKM8() asm volatile("s_waitcnt lgkmcnt(8)" ::: "memory")
#define VMW(n)  asm volatile("s_waitcnt vmcnt(" #n ")" ::: "memory")
#define SCHED0() __builtin_amdgcn_sched_barrier(0)

template <int MODE>
__global__ __launch_bounds__(512, 2) void k_gemm8(
    const __hip_bfloat16* __restrict__ A, int lda, long long strideA,
    const __hip_bfloat16* __restrict__ Bt, int ldb, long long strideB,
    const float* __restrict__ bias, int strideBias,
    void* __restrict__ out, int ldo, long long strideOut, int K)
{
    __shared__ __hip_bfloat16 sA[2][2][128 * 64];   // 64 KB
    __shared__ __hip_bfloat16 sB[2][2][128 * 64];   // 64 KB

    const int z = blockIdx.z;
    A  += (size_t)z * (size_t)strideA;
    Bt += (size_t)z * (size_t)strideB;

    const int tid  = threadIdx.x;
    const int lane = tid & 63;
    const int wid  = tid >> 6;
    const int wr = wid >> 2, wc = wid & 3;          // 2 x 4 waves
    const int m0 = blockIdx.y * 256, n0 = blockIdx.x * 256;

    // ---- staging: dest linear (tid*16); source col pre-swizzled by involution kbyte ^= (row&7)<<4
    const int sr  = tid >> 3;
    const int skb = ((((tid & 7) * 16) ^ ((sr & 7) << 4)) >> 1);
    const __hip_bfloat16* gA = A  + (size_t)(m0 + sr) * lda + skb;
    const __hip_bfloat16* gB = Bt + (size_t)(n0 + sr) * ldb + skb;
    char* const dA = (char*)&sA[0][0][0] + tid * 16;
    char* const dB = (char*)&sB[0][0][0] + tid * 16;

#define STAGE_A(bb, hh, kt) do { \
    const __hip_bfloat16* s_ = gA + (size_t)(hh) * 128 * lda + (size_t)(kt) * 64; \
    gload_lds16(s_,                     dA + (bb) * 32768 + (hh) * 16384); \
    gload_lds16(s_ + (size_t)64 * lda,  dA + (bb) * 32768 + (hh) * 16384 + 8192); \
} while (0)
#define STAGE_B(bb, hh, kt) do { \
    const __hip_bfloat16* s_ = gB + (size_t)(hh) * 128 * ldb + (size_t)(kt) * 64; \
    gload_lds16(s_,                     dB + (bb) * 32768 + (hh) * 16384); \
    gload_lds16(s_ + (size_t)64 * ldb,  dB + (bb) * 32768 + (hh) * 16384 + 8192); \
} while (0)

    // ---- ds_read fragment addressing (swizzled)
    const int fr = lane & 15, kg = lane >> 4;
    const int msk  = (fr & 7) << 4;
    const int kof0 = (kg * 16) ^ msk;
    const int kof1 = (64 + kg * 16) ^ msk;
    const char* rdA = (const char*)&sA[0][wr][0] + fr * 128;
    const char* rdB = (const char*)&sB[0][wc >> 1][0] + (wc & 1) * 8192 + fr * 128;

    f32x4  acc[8][4] = {};
    bf16x8 aL[4][2], aH[4][2], bL[2][2], bH[2][2];

    const int NT = K >> 6;                          // K-tiles of 64 (even, >= 4)

    // ---- prologue: stage T0 (B,A) and T1 (B). 12 issued, VMW(4) lands T0, leaves B(1) in flight.
    STAGE_B(0, 0, 0); STAGE_B(0, 1, 0);
    STAGE_A(0, 0, 0); STAGE_A(0, 1, 0);
    STAGE_B(1, 0, 1); STAGE_B(1, 1, 1);
    VMW(4); BAR(); SCHED0();

    for (int i = 0; i < NT / 2 - 1; ++i) {
        const int t1 = 2 * i + 1;
        // ===== K-tile t0 (buf0); stages: A(t1)->buf1 @p0/p1, B(t1+1)->buf0 @p2/p3
        ld_a<0, 0>(aL, rdA, kof0, kof1);            // p0: 12 ds_reads
        ld_b<0, 0>(bL, rdB, kof0, kof1);
        STAGE_A(1, 0, t1);
        LGKM8(); SCHED0();
        BAR(); LGKM0(); SCHED0();
        mfma_q<0, 0>(aL, bL, acc);
        BAR();
        ld_b<0, 2>(bH, rdB, kof0, kof1);            // p1: 4 ds_reads
        STAGE_A(1, 1, t1);
        SCHED0();
        BAR(); LGKM0(); SCHED0();
        mfma_q<0, 2>(aL, bH, acc);
        BAR();
        ld_a<0, 4>(aH, rdA, kof0, kof1);            // p2: 8 ds_reads
        STAGE_B(0, 0, t1 + 1);
        SCHED0();
        BAR(); LGKM0(); SCHED0();
        mfma_q<4, 0>(aH, bL, acc);
        BAR();
        STAGE_B(0, 1, t1 + 1);                      // p3: 0 ds_reads
        SCHED0();
        BAR();
        mfma_q<4, 2>(aH, bH, acc);
        VMW(4); BAR(); SCHED0();
        // ===== K-tile t1 (buf1); stages: A(t1+1)->buf0 @p0/p1, B(t1+2)->buf1 @p2/p3
        ld_a<1, 0>(aL, rdA, kof0, kof1);
        ld_b<1, 0>(bL, rdB, kof0, kof1);
        STAGE_A(0, 0, t1 + 1);
        LGKM8(); SCHED0();
        BAR(); LGKM0(); SCHED0();
        mfma_q<0, 0>(aL, bL, acc);
        BAR();
        ld_b<1, 2>(bH, rdB, kof0, kof1);
        STAGE_A(0, 1, t1 + 1);
        SCHED0();
        BAR(); LGKM0(); SCHED0();
        mfma_q<0, 2>(aL, bH, acc);
        BAR();
        ld_a<1, 4>(aH, rdA, kof0, kof1);
        STAGE_B(1, 0, t1 + 2);
        SCHED0();
        BAR(); LGKM0(); SCHED0();
        mfma_q<4, 0>(aH, bL, acc);
        BAR();
        STAGE_B(1, 1, t1 + 2);
        SCHED0();
        BAR();
        mfma_q<4, 2>(aH, bH, acc);
        VMW(4); BAR(); SCHED0();
    }
    {   // ---- tail: tile NT-2 (buf0; stage only A(NT-1)->buf1), drain, tile NT-1 (buf1)
        const int t1 = NT - 1;
        ld_a<0, 0>(aL, rdA, kof0, kof1);
        ld_b<0, 0>(bL, rdB, kof0, kof1);
        STAGE_A(1, 0, t1);
        LGKM8(); SCHED0();
        BAR(); LGKM0(); SCHED0();
        mfma_q<0, 0>(aL, bL, acc);
        BAR();
        ld_b<0, 2>(bH, rdB, kof0, kof1);
        STAGE_A(1, 1, t1);
        SCHED0();
        BAR(); LGKM0(); SCHED0();
        mfma_q<0, 2>(aL, bH, acc);
        BAR();
        ld_a<0, 4>(aH, rdA, kof0, kof1);
        SCHED0();
        BAR(); LGKM0(); SCHED0();
        mfma_q<4, 0>(aH, bL, acc);
        BAR();
        mfma_q<4, 2>(aH, bH, acc);
        VMW(0); BAR(); SCHED0();
        // tile NT-1 (buf1): reads only, no barriers needed (nothing overwrites LDS after drain)
        ld_a<1, 0>(aL, rdA, kof0, kof1);
        ld_b<1, 0>(bL, rdB, kof0, kof1);
        LGKM0(); SCHED0();
        mfma_q<0, 0>(aL, bL, acc);
        ld_b<1, 2>(bH, rdB, kof0, kof1);
        LGKM0(); SCHED0();
        mfma_q<0, 2>(aL, bH, acc);
        ld_a<1, 4>(aH, rdA, kof0, kof1);
        LGKM0(); SCHED0();
        mfma_q<4, 0>(aH, bL, acc);
        mfma_q<4, 2>(aH, bH, acc);
    }

    // ---- epilogue. C-frag layout: col = lane&15 (fr), row = kg*4 + j  [m89-verified]
    const int rB = kg * 4;
    if (MODE == 0) {
        __hip_bfloat16* O = (__hip_bfloat16*)out + (size_t)z * (size_t)strideOut;
        const float* bz = bias + (size_t)z * (size_t)strideBias;
#pragma unroll
        for (int mi = 0; mi < 8; ++mi) {
            const int gm = m0 + wr * 128 + mi * 16 + rB;
#pragma unroll
            for (int ni = 0; ni < 4; ++ni) {
                const int gn = n0 + wc * 64 + ni * 16 + fr;
                const float bv = bz[gn];
#pragma unroll
                for (int j = 0; j < 4; ++j) {
                    float v = acc[mi][ni][j] + bv;
                    v = v / (1.f + __expf(-v));        // silu
                    O[(size_t)(gm + j) * ldo + gn] = __float2bfloat16(v);
                }
            }
        }
    } else {
        float* O = (float*)out + (size_t)z * (size_t)strideOut;
#pragma unroll
        for (int mi = 0; mi < 8; ++mi) {
            const int gm = m0 + wr * 128 + mi * 16 + rB;
#pragma unroll
            for (int ni = 0; ni < 4; ++ni) {
                const int gn = n0 + wc * 64 + ni * 16 + fr;
#pragma unroll
                for (int j = 0; j < 4; ++j)
                    O[(size_t)(gm + j) * ldo + gn] = acc[mi][ni][j];
            }
        }
    }
#undef STAGE_A
#undef STAGE_B
}

// -------- combine: x[t,h] += sum_j rw[t,e0+j]*(eo[j][t][h] + b2[e0+j][h]). 1 block/token.
__global__ __launch_bounds__(256) void k_combine(
    const float* __restrict__ eo, const float* __restrict__ rw,
    const float* __restrict__ b2, float* __restrict__ x, int e0, int g)
{
    const int t = blockIdx.x;
    const int h = threadIdx.x * 4;
    float4 acc = *(const float4*)(x + (size_t)t * H_DIM + h);
    for (int j = 0; j < g; ++j) {
        const float w = rw[(size_t)t * E_EXP + e0 + j];
        const float4 v  = *(const float4*)(eo + ((size_t)j * T_TOK + t) * H_DIM + h);
        const float4 bz = *(const float4*)(b2 + (size_t)(e0 + j) * H_DIM + h);
        acc.x += w * (v.x + bz.x);
        acc.y += w * (v.y + bz.y);
        acc.z += w * (v.z + bz.z);
        acc.w += w * (v.w + bz.w);
    }
    *(float4*)(x + (size_t)t * H_DIM + h) = acc;
}

extern "C" void kernel_launch(void* const* d_in, const int* in_sizes, int n_in,
                              void* d_out, int out_size, void* d_ws, size_t ws_size,
                              hipStream_t stream)
{
    const float* hidden = (const float*)d_in[0];
    const float* gate_w = (const float*)d_in[1];
    const float* w1     = (const float*)d_in[2];
    const float* b1     = (const float*)d_in[3];
    const float* w2     = (const float*)d_in[4];
    const float* b2     = (const float*)d_in[5];
    const float* ln_w   = (const float*)d_in[6];
    float* x = (float*)d_out;

    // workspace carve
    const size_t w1t_b = (size_t)E_EXP * I_DIM * H_DIM * 2;   // 64 MB
    const size_t w2t_b = (size_t)E_EXP * H_DIM * I_DIM * 2;   // 64 MB
    const size_t tb_b  = (size_t)T_TOK * H_DIM * 2;           //  8 MB
    const size_t rw_b  = (size_t)T_TOK * E_EXP * 4;           // 128 KB
    const size_t hb1_b = (size_t)T_TOK * I_DIM * 2;           // 32 MB per expert
    const size_t eo1_b = (size_t)T_TOK * H_DIM * 4;           // 16 MB per expert
    const size_t base_b = w1t_b + w2t_b + tb_b + rw_b;

    // largest expert group that fits
    int g = 0;
    for (int cand = 8; cand >= 1; cand >>= 1)
        if (base_b + (size_t)cand * (hb1_b + eo1_b) <= ws_size) { g = cand; break; }

    char* ws = (char*)d_ws;
    __hip_bfloat16* w1t = (__hip_bfloat16*)ws;  ws += w1t_b;
    __hip_bfloat16* w2t = (__hip_bfloat16*)ws;  ws += w2t_b;
    __hip_bfloat16* tb  = (__hip_bfloat16*)ws;  ws += tb_b;
    float*          rw  = (float*)ws;           ws += rw_b;
    __hip_bfloat16* hb  = (__hip_bfloat16*)ws;
    float*          eo  = (float*)(ws + (size_t)(g > 0 ? g : 1) * hb1_b);

    // x = hidden_states (running residual lives in d_out)
    hipMemcpyAsync(x, hidden, (size_t)T_TOK * H_DIM * 4, hipMemcpyDeviceToDevice, stream);

    if (g == 0) return;  // ws too small (harness has given >= 232 MB so far)

    // bf16 weights in B^T layout: w1t [E][I][H], w2t [E][H][I]
    k_transpose_cvt<<<dim3(I_DIM / 32, H_DIM / 32, E_EXP), 256, 0, stream>>>(w1, w1t, H_DIM, I_DIM);
    k_transpose_cvt<<<dim3(H_DIM / 32, I_DIM / 32, E_EXP), 256, 0, stream>>>(w2, w2t, I_DIM, H_DIM);

    for (int step = 0; step < 2; ++step) {
        k_prep<<<T_TOK, 256, 0, stream>>>(x, ln_w, tb, step);
        k_gate<<<T_TOK / 4, 256, 0, stream>>>(tb, gate_w, rw);

        for (int e0 = 0; e0 < E_EXP; e0 += g) {
            // GEMM1: hb[j] = silu(tb @ w1t[e0+j]^T + b1[e0+j]),  M=T, N=I, K=H
            k_gemm8<0><<<dim3(I_DIM / 256, T_TOK / 256, g), 512, 0, stream>>>(
                tb, H_DIM, 0,
                w1t + (size_t)e0 * I_DIM * H_DIM, H_DIM, (long long)I_DIM * H_DIM,
                b1 + (size_t)e0 * I_DIM, I_DIM,
                hb, I_DIM, (long long)T_TOK * I_DIM, H_DIM);
            // GEMM2: eo[j] = hb[j] @ w2t[e0+j]^T  (raw fp32 partials), M=T, N=H, K=I
            k_gemm8<2><<<dim3(H_DIM / 256, T_TOK / 256, g), 512, 0, stream>>>(
                hb, I_DIM, (long long)T_TOK * I_DIM,
                w2t + (size_t)e0 * H_DIM * I_DIM, I_DIM, (long long)H_DIM * I_DIM,
                nullptr, 0,
                eo, H_DIM, (long long)T_TOK * H_DIM, I_DIM);
            // x += sum_j rw[:,e0+j]*(eo[j] + b2[e0+j])
            k_combine<<<T_TOK, 256, 0, stream>>>(eo, rw, b2, x, e0, g);
        }
    }
}